// Round 9
// baseline (232.604 us; speedup 1.0000x reference)
//
#include <hip/hip_runtime.h>

#define NDFF 2048
#define NVOC 10000
#define SIGMA 0.1f

typedef float f32x4 __attribute__((ext_vector_type(4)));

// ---- output offsets (floats) ----
#define O0 0
#define O1 65536
#define O2 131072
#define O3 211072
#define O4 291072
#define O5 371072
#define O6 436608
#define O7 502144
#define O8 34056576
#define O9 67611008
#define O10 67611136

// ---- workspace offsets (floats) ----
#define WQ    0
#define WK    65536
#define WV    131072
#define WZH   196608
#define WZ    262144
#define WO1   327680
#define WH1   393216
#define WPRED 720896
#define WMAX  2000896
#define WSUM  2001024
#define WWSQ  2001152
#define WIT   2001280
#define WF2P  2001536
#define WSC   2263680

// ===== s>t copy helper: quarter q of rows s in (t, 511], NT streaming =====
__device__ __forceinline__ void copy_sgt(const float* __restrict__ Kin,
                                         float* __restrict__ out, int t,
                                         int q, int bid, int nblk, int tid, int nthr)
{
    const f32x4* K4 = (const f32x4*)Kin;
    f32x4* oK = (f32x4*)(out + O7);
    f32x4* oV = (f32x4*)(out + O8);
    int cnt = 511 - t;
    long totalc = (long)128 * cnt * 128;
    long q0 = (totalc * q) >> 2, q1 = (totalc * (q + 1)) >> 2;
    for (long j = q0 + (long)bid * nthr + tid; j < q1; j += (long)nblk * nthr) {
        int lane = (int)(j & 127);
        long row = j >> 7;                 // bp*cnt + (s - t - 1)
        int bp = (int)(row / cnt);
        int s = t + 1 + (int)(row - (long)bp * cnt);
        long i = ((long)(bp * 512 + s) << 7) + lane;
        f32x4 v = __builtin_nontemporal_load(&K4[i]);
        __builtin_nontemporal_store(v, &oK[i]);
        __builtin_nontemporal_store(v, &oV[i]);
    }
}

// ===== QKV projection. grid (8, 16, 3), 512 thr; 8-way K-split =====
__global__ __launch_bounds__(512)
void k_qkv(const float* __restrict__ r,
           const float* __restrict__ Wq, const float* __restrict__ bq, const float* __restrict__ eq, float* __restrict__ oq,
           const float* __restrict__ Wk, const float* __restrict__ bk, const float* __restrict__ ek, float* __restrict__ ok,
           const float* __restrict__ Wv, const float* __restrict__ bv, const float* __restrict__ ev, float* __restrict__ ov)
{
    const float *W, *bias, *eps; float* out;
    if (blockIdx.z == 0)      { W = Wq; bias = bq; eps = eq; out = oq; }
    else if (blockIdx.z == 1) { W = Wk; bias = bk; eps = ek; out = ok; }
    else                      { W = Wv; bias = bv; eps = ev; out = ov; }
    int tid = threadIdx.x;
    int col = tid & 63, kq = tid >> 6;
    int colg = blockIdx.x * 64 + col;
    int row0 = blockIdx.y * 8;
    __shared__ float rs[8][512];
#pragma unroll
    for (int j = 0; j < 8; j++) rs[j][tid & 511] = r[(row0 + j) * 512 + tid];
    __syncthreads();
    float acc[8] = {0,0,0,0,0,0,0,0};
    const float* Wp = W + (kq * 64) * 512 + colg;
#pragma unroll 8
    for (int d = 0; d < 64; d++) {
        float wv = Wp[d * 512];
#pragma unroll
        for (int p = 0; p < 8; p++) acc[p] += rs[p][kq * 64 + d] * wv;
    }
    __syncthreads();
    float (*part)[8][64] = (float(*)[8][64])rs;
#pragma unroll
    for (int p = 0; p < 8; p++) part[kq][p][col] = acc[p];
    __syncthreads();
    {
        int p = tid >> 6, c = tid & 63;
        int cg = blockIdx.x * 64 + c;
        float v = 0.f;
#pragma unroll
        for (int k = 0; k < 8; k++) v += part[k][p][c];
        out[(row0 + p) * 512 + cg] = v + bias[cg] + SIGMA * eps[(row0 + p) * 512 + cg];
    }
}

// ===== fused attention. grid (128, 8), 512 thr =====
__global__ __launch_bounds__(512)
void k_attn(const float* __restrict__ qws, const float* __restrict__ kws,
            const float* __restrict__ vws, const float* __restrict__ Kin,
            const float* __restrict__ Vin, const int* __restrict__ t_ptr,
            float* __restrict__ zh, float* __restrict__ scw)
{
    int t = *t_ptr;
    int bp = blockIdx.x, h = blockIdx.y;
    int tid = threadIdx.x;
    int wave = tid >> 6, lane = tid & 63;
    __shared__ float sc[512];
    __shared__ float red[8], red2[8];
    __shared__ float part[8][64];

    float4 qv = ((const float4*)(qws + bp * 512 + h * 64))[lane & 15];

    for (int sb = wave * 4; sb <= t; sb += 32) {
        int s = sb + (lane >> 4);
        bool valid = (s <= t);
        int ss = valid ? s : t;
        const float4* kr = (ss == t) ? (const float4*)(kws + bp * 512 + h * 64)
                                     : (const float4*)(Kin + (bp * 512 + ss) * 512 + h * 64);
        float4 kv = kr[lane & 15];
        float p = qv.x * kv.x + qv.y * kv.y + qv.z * kv.z + qv.w * kv.w;
#pragma unroll
        for (int m = 1; m < 16; m <<= 1) p += __shfl_xor(p, m, 64);
        if ((lane & 15) == 0 && valid) sc[s] = p * 0.125f;
    }
    __syncthreads();

    float lm = -3.0e38f;
    for (int s = tid; s <= t; s += 512) lm = fmaxf(lm, sc[s]);
#pragma unroll
    for (int o = 32; o; o >>= 1) lm = fmaxf(lm, __shfl_xor(lm, o, 64));
    if (lane == 0) red[wave] = lm;
    __syncthreads();
    float m = red[0];
#pragma unroll
    for (int i = 1; i < 8; i++) m = fmaxf(m, red[i]);
    float ls = 0.f;
    for (int s = tid; s <= t; s += 512) ls += __expf(sc[s] - m);
#pragma unroll
    for (int o = 32; o; o >>= 1) ls += __shfl_xor(ls, o, 64);
    if (lane == 0) red2[wave] = ls;
    __syncthreads();
    float tot = 0.f;
#pragma unroll
    for (int i = 0; i < 8; i++) tot += red2[i];
    float inv = 1.f / tot;
    for (int s = tid; s <= t; s += 512) {
        float a = __expf(sc[s] - m) * inv;
        sc[s] = a;
        scw[(bp * 8 + h) * 512 + s] = a;
    }
    __syncthreads();

    float acc = 0.f;
    const float* Vp = Vin + (bp * 512) * 512 + h * 64 + lane;
    int s = wave;
    for (; s + 24 < t; s += 32) {
        float v0 = __builtin_nontemporal_load(Vp + (size_t)(s     ) * 512);
        float v1 = __builtin_nontemporal_load(Vp + (size_t)(s +  8) * 512);
        float v2 = __builtin_nontemporal_load(Vp + (size_t)(s + 16) * 512);
        float v3 = __builtin_nontemporal_load(Vp + (size_t)(s + 24) * 512);
        acc += sc[s] * v0 + sc[s + 8] * v1 + sc[s + 16] * v2 + sc[s + 24] * v3;
    }
    for (; s < t; s += 8) acc += sc[s] * __builtin_nontemporal_load(Vp + (size_t)s * 512);
    if ((t & 7) == wave) acc += sc[t] * vws[bp * 512 + h * 64 + lane];
    part[wave][lane] = acc;
    __syncthreads();
    if (tid < 64) {
        float v = 0.f;
#pragma unroll
        for (int k = 0; k < 8; k++) v += part[k][tid];
        zh[bp * 512 + h * 64 + tid] = v;
    }
}

// ===== z projection + copy q0. grid (12, 16), 512 thr =====
__global__ __launch_bounds__(512)
void k_zproj(const float* __restrict__ zh, const float* __restrict__ Wo,
             const float* __restrict__ bo, const float* __restrict__ epsz,
             const float* __restrict__ Kin, const int* __restrict__ t_ptr,
             float* __restrict__ outbuf, float* __restrict__ out)
{
    if (blockIdx.x >= 8) {
        int bid = (blockIdx.x - 8) * 16 + blockIdx.y;
        copy_sgt(Kin, outbuf, *t_ptr, 0, bid, 64, threadIdx.x, 512);
        return;
    }
    int tid = threadIdx.x;
    int col = tid & 63, kq = tid >> 6;
    int colg = blockIdx.x * 64 + col;
    int row0 = blockIdx.y * 8;
    __shared__ float rs[8][512];
#pragma unroll
    for (int j = 0; j < 8; j++) rs[j][tid] = zh[(row0 + j) * 512 + tid];
    __syncthreads();
    float acc[8] = {0,0,0,0,0,0,0,0};
    const float* Wp = Wo + (kq * 64) * 512 + colg;
#pragma unroll 8
    for (int d = 0; d < 64; d++) {
        float wv = Wp[d * 512];
#pragma unroll
        for (int p = 0; p < 8; p++) acc[p] += rs[p][kq * 64 + d] * wv;
    }
    __syncthreads();
    float (*part)[8][64] = (float(*)[8][64])rs;
#pragma unroll
    for (int p = 0; p < 8; p++) part[kq][p][col] = acc[p];
    __syncthreads();
    {
        int p = tid >> 6, c = tid & 63;
        int cg = blockIdx.x * 64 + c;
        float v = 0.f;
#pragma unroll
        for (int k = 0; k < 8; k++) v += part[k][p][c];
        out[(row0 + p) * 512 + cg] = v + bo[cg] + SIGMA * epsz[(row0 + p) * 512 + cg];
    }
}

// ===== ffn1 + fused LN1 + copy q1. grid (36, 16), 512 thr =====
__global__ __launch_bounds__(512)
void k_ffn1(const float* __restrict__ zp, const float* __restrict__ r,
            const float* __restrict__ g, const float* __restrict__ be,
            const float* __restrict__ W1, const float* __restrict__ b1,
            const float* __restrict__ Kin, const int* __restrict__ t_ptr,
            float* __restrict__ outbuf,
            float* __restrict__ o1, float* __restrict__ h1)
{
    if (blockIdx.x >= 32) {
        int bid = (blockIdx.x - 32) * 16 + blockIdx.y;
        copy_sgt(Kin, outbuf, *t_ptr, 1, bid, 64, threadIdx.x, 512);
        return;
    }
    int tid = threadIdx.x;
    int col = tid & 63, kq = tid >> 6;
    int colg = blockIdx.x * 64 + col;
    int row0 = blockIdx.y * 8;
    __shared__ float rs[8][512];
    __shared__ float sm[8], si[8];
    int wave = tid >> 6, lane = tid & 63;
#pragma unroll
    for (int j = 0; j < 8; j++) {
        int gi = (row0 + j) * 512 + tid;
        rs[j][tid] = zp[gi] + r[gi];
    }
    __syncthreads();
    {
        float s = 0.f;
        for (int c = lane; c < 512; c += 64) s += rs[wave][c];
#pragma unroll
        for (int o = 32; o; o >>= 1) s += __shfl_xor(s, o, 64);
        float mu = s * (1.f / 512.f);
        float v = 0.f;
        for (int c = lane; c < 512; c += 64) { float dx = rs[wave][c] - mu; v += dx * dx; }
#pragma unroll
        for (int o = 32; o; o >>= 1) v += __shfl_xor(v, o, 64);
        if (lane == 0) { sm[wave] = mu; si[wave] = rsqrtf(v * (1.f / 512.f) + 1e-6f); }
    }
    __syncthreads();
#pragma unroll
    for (int j = 0; j < 8; j++) {
        float val = (rs[j][tid] - sm[j]) * si[j] * g[tid] + be[tid];
        rs[j][tid] = val;
        if (blockIdx.x == 0) o1[(row0 + j) * 512 + tid] = val;
    }
    __syncthreads();
    float acc[8] = {0,0,0,0,0,0,0,0};
    const float* Wp = W1 + (kq * 64) * NDFF + colg;
#pragma unroll 8
    for (int d = 0; d < 64; d++) {
        float wv = Wp[d * NDFF];
#pragma unroll
        for (int p = 0; p < 8; p++) acc[p] += rs[p][kq * 64 + d] * wv;
    }
    __syncthreads();
    float (*part)[8][64] = (float(*)[8][64])rs;
#pragma unroll
    for (int p = 0; p < 8; p++) part[kq][p][col] = acc[p];
    __syncthreads();
    {
        int p = tid >> 6, c = tid & 63;
        int cg = blockIdx.x * 64 + c;
        float v = 0.f;
#pragma unroll
        for (int k = 0; k < 8; k++) v += part[k][p][c];
        h1[(row0 + p) * NDFF + cg] = fmaxf(v + b1[cg], 0.f);
    }
}

// ===== ffn2 partials + copy q2. grid (9, 16, 4), 512 thr =====
__global__ __launch_bounds__(512)
void k_ffn2p(const float* __restrict__ h1, const float* __restrict__ W2,
             const float* __restrict__ Kin, const int* __restrict__ t_ptr,
             float* __restrict__ outbuf, float* __restrict__ f2p)
{
    if (blockIdx.x >= 8) {
        int bid = blockIdx.y * 4 + blockIdx.z;
        copy_sgt(Kin, outbuf, *t_ptr, 2, bid, 64, threadIdx.x, 512);
        return;
    }
    int tid = threadIdx.x;
    int col = tid & 63, kq = tid >> 6;
    int colg = blockIdx.x * 64 + col;
    int row0 = blockIdx.y * 8;
    int ks = blockIdx.z;
    __shared__ float rs[8][512];
#pragma unroll
    for (int j = 0; j < 8; j++)
        rs[j][tid] = h1[(row0 + j) * NDFF + ks * 512 + tid];
    __syncthreads();
    float acc[8] = {0,0,0,0,0,0,0,0};
    const float* Wp = W2 + (ks * 512 + kq * 64) * 512 + colg;
#pragma unroll 8
    for (int d = 0; d < 64; d++) {
        float wv = Wp[d * 512];
#pragma unroll
        for (int p = 0; p < 8; p++) acc[p] += rs[p][kq * 64 + d] * wv;
    }
    __syncthreads();
    float (*part)[8][64] = (float(*)[8][64])rs;
#pragma unroll
    for (int p = 0; p < 8; p++) part[kq][p][col] = acc[p];
    __syncthreads();
    {
        int p = tid >> 6, c = tid & 63;
        int cg = blockIdx.x * 64 + c;
        float v = 0.f;
#pragma unroll
        for (int k = 0; k < 8; k++) v += part[k][p][c];
        f2p[ks * 65536 + (row0 + p) * 512 + cg] = v;
    }
}

// ===== pred + fused LN3 + copy q3. grid (48, 8), 512 thr =====
__global__ __launch_bounds__(512)
void k_pred(const float* __restrict__ f2p, const float* __restrict__ b2,
            const float* __restrict__ o1, const float* __restrict__ g3,
            const float* __restrict__ b3, const float* __restrict__ Wout,
            const float* __restrict__ bout,
            const float* __restrict__ Kin, const int* __restrict__ t_ptr,
            float* __restrict__ outbuf, float* __restrict__ pred)
{
    if (blockIdx.x >= 40) {
        int bid = (blockIdx.x - 40) * 8 + blockIdx.y;
        copy_sgt(Kin, outbuf, *t_ptr, 3, bid, 64, threadIdx.x, 512);
        return;
    }
    int tid = threadIdx.x;
    int col = tid & 255, kh = tid >> 8;
    int colg = blockIdx.x * 256 + col;
    int colL = min(colg, NVOC - 1);
    int row0 = blockIdx.y * 16;
    __shared__ float rs[16][512];
    __shared__ float sm[16], si[16];
    int wave = tid >> 6, lane = tid & 63;
#pragma unroll
    for (int j = 0; j < 16; j++) {
        int gi = (row0 + j) * 512 + tid;
        rs[j][tid] = f2p[gi] + f2p[65536 + gi] + f2p[131072 + gi] + f2p[196608 + gi]
                   + b2[tid] + o1[gi];
    }
    __syncthreads();
    {
        int row = wave * 2 + (lane >> 5);
        int l = lane & 31;
        float s = 0.f;
        for (int c = l; c < 512; c += 32) s += rs[row][c];
#pragma unroll
        for (int o = 16; o; o >>= 1) s += __shfl_xor(s, o, 64);
        float mu = s * (1.f / 512.f);
        float v = 0.f;
        for (int c = l; c < 512; c += 32) { float dx = rs[row][c] - mu; v += dx * dx; }
#pragma unroll
        for (int o = 16; o; o >>= 1) v += __shfl_xor(v, o, 64);
        if (l == 0) { sm[row] = mu; si[row] = rsqrtf(v * (1.f / 512.f) + 1e-6f); }
    }
    __syncthreads();
#pragma unroll
    for (int j = 0; j < 16; j++)
        rs[j][tid] = (rs[j][tid] - sm[j]) * si[j] * g3[tid] + b3[tid];
    __syncthreads();
    float acc[16];
#pragma unroll
    for (int p = 0; p < 16; p++) acc[p] = 0.f;
    const float* Wp = Wout + (kh * 256) * NVOC + colL;
#pragma unroll 4
    for (int d = 0; d < 256; d++) {
        float wv = Wp[d * NVOC];
#pragma unroll
        for (int p = 0; p < 16; p++) acc[p] += rs[p][kh * 256 + d] * wv;
    }
    __syncthreads();
    float (*part)[256] = (float(*)[256])rs;
    if (kh == 1) {
#pragma unroll
        for (int p = 0; p < 16; p++) part[p][col] = acc[p];
    }
    __syncthreads();
    if (kh == 0 && colg < NVOC) {
        float bv = bout[colg];
#pragma unroll
        for (int p = 0; p < 16; p++)
            pred[(row0 + p) * NVOC + colg] = acc[p] + part[p][col] + bv;
    }
}

// ===== per-row softmax stats + w_sq + attn_weights. grid 128, 512 thr =====
__global__ __launch_bounds__(512)
void k_soft(const float* __restrict__ pred, const int* __restrict__ x,
            const float* __restrict__ scw, const int* __restrict__ t_ptr,
            float* __restrict__ rowmax, float* __restrict__ rowsum,
            float* __restrict__ wsq, float* __restrict__ out)
{
    __shared__ float red[8];
    int row = blockIdx.x, tid = threadIdx.x;
    {
        int t = *t_ptr;
        float a = 0.f;
        if (tid <= t) {
#pragma unroll
            for (int hh = 0; hh < 8; hh++) a += scw[(row * 8 + hh) * 512 + tid];
            a *= 0.125f;
        }
        out[O6 + row * 512 + tid] = a;
    }
    const float* pr = pred + row * NVOC;
    float m = -3.0e38f;
    for (int v = tid; v < NVOC; v += 512) m = fmaxf(m, pr[v]);
#pragma unroll
    for (int o = 32; o; o >>= 1) m = fmaxf(m, __shfl_xor(m, o, 64));
    if ((tid & 63) == 0) red[tid >> 6] = m;
    __syncthreads();
#pragma unroll
    for (int i = 0; i < 8; i++) m = fmaxf(m, red[i]);
    __syncthreads();
    float s = 0.f;
    for (int v = tid; v < NVOC; v += 512) s += __expf(pr[v] - m);
#pragma unroll
    for (int o = 32; o; o >>= 1) s += __shfl_xor(s, o, 64);
    if ((tid & 63) == 0) red[tid >> 6] = s;
    __syncthreads();
    if (tid == 0) {
        float tot = 0.f;
#pragma unroll
        for (int i = 0; i < 8; i++) tot += red[i];
        rowmax[row] = m; rowsum[row] = tot;
        int b = row >> 4;
        float w = __expf(pr[x[b]] - m) / tot;
        wsq[row] = w;
        out[O9 + row] = w;
    }
}

// ===== vocab outputs + it/amw. grid (20, 8), 512 thr =====
__global__ __launch_bounds__(512)
void k_vocab(const float* __restrict__ pred, const float* __restrict__ rowmax,
             const float* __restrict__ rowsum, const float* __restrict__ wsq,
             const float* __restrict__ gumbel, int* __restrict__ it,
             float* __restrict__ out)
{
    int b = blockIdx.y;
    int tid = threadIdx.x;
    __shared__ int s_amw;
    if (tid == 0) {
        float bw = -3.0e38f; int bj = 0;
#pragma unroll
        for (int pp = 0; pp < 16; pp++) {
            float wv = wsq[b * 16 + pp];
            if (wv > bw) { bw = wv; bj = pp; }
        }
        s_amw = bj;
    }
    if (blockIdx.x == 0 && tid < 16) {
        float best = -3.0e38f; int bi = 0;
#pragma unroll
        for (int pp = 0; pp < 16; pp++) {
            float v = logf(wsq[b * 16 + pp] + 1e-10f) + gumbel[(b * 16 + tid) * 16 + pp];
            if (v > best) { best = v; bi = pp; }
        }
        it[b * 16 + tid] = bi;
    }
    __syncthreads();
    int v = blockIdx.x * 512 + tid;
    if (v >= NVOC) return;
    int amw = s_amw;
    float ga = 0.f, as = 0.f;
#pragma unroll
    for (int p = 0; p < 16; p++) {
        int rr = b * 16 + p;
        float pv = pred[rr * NVOC + v];
        ga += pv;
        as += __expf(pv - rowmax[rr]) * (1.f / rowsum[rr]);
    }
    out[O3 + b * NVOC + v] = ga * (1.f / 16.f);
    out[O2 + b * NVOC + v] = as * (1.f / 16.f);
    out[O4 + b * NVOC + v] = pred[(b * 16 + amw) * NVOC + v];
}

// ===== K / Vs gather (s<=t only) + misc outputs. grid 2048 x 256 =====
__global__ __launch_bounds__(256)
void k_resample(const float* __restrict__ Kin, const float* __restrict__ kws,
                const int* __restrict__ it, const int* __restrict__ t_ptr,
                const float* __restrict__ r, const float* __restrict__ epsz,
                const float* __restrict__ zws, const int* __restrict__ Iin,
                float* __restrict__ out)
{
    int t = *t_ptr;
    const f32x4* K4  = (const f32x4*)Kin;
    const f32x4* kw4 = (const f32x4*)kws;
    const f32x4* r4  = (const f32x4*)r;
    const f32x4* e4  = (const f32x4*)epsz;
    const f32x4* z4  = (const f32x4*)zws;
    f32x4* oK = (f32x4*)(out + O7);
    f32x4* oV = (f32x4*)(out + O8);
    int cnt = t + 1;                        // rows with s <= t
    long total = (long)128 * cnt * 128;
    long total2 = total + 16384;
    for (long j = (long)blockIdx.x * 256 + threadIdx.x; j < total2; j += (long)gridDim.x * 256) {
        if (j < total) {
            int lane = (int)(j & 127);
            long row = j >> 7;              // bp*cnt + s
            int bp = (int)(row / cnt);
            int s = (int)(row - (long)bp * cnt);
            int b = bp >> 4;
            int ip = it[bp];
            int ip2 = it[b * 16 + ip];
            f32x4 vK, vV;
            if (s == t) {
                vK = kw4[(b * 16 + ip) * 128 + lane];
                vV = kw4[(b * 16 + ip2) * 128 + lane];
            } else {
                vK = K4[((long)((b * 16 + ip) * 512 + s) << 7) + lane];
                vV = K4[((long)((b * 16 + ip2) * 512 + s) << 7) + lane];
            }
            long i = ((long)(bp * 512 + s) << 7) + lane;
            __builtin_nontemporal_store(vK, &oK[i]);
            __builtin_nontemporal_store(vV, &oV[i]);
        } else {
            int jj = (int)(j - total);
            int fidx = jj * 4;
            ((f32x4*)(out + O0))[jj] = r4[jj];
            ((f32x4*)(out + O5))[jj] = e4[jj];
            int row = fidx >> 9, d0 = fidx & 511;
            int b = row >> 4;
            int ip = it[row];
            ((f32x4*)(out + O1))[jj] = z4[((b * 16 + ip) << 7) + (d0 >> 2)];
#pragma unroll
            for (int k = 0; k < 4; k++) {
                int s = d0 + k;
                float iv;
                if (s < t)       iv = (float)Iin[((b * 16 + ip) << 9) + s];
                else if (s == t) iv = (float)ip;
                else             iv = (float)Iin[row * 512 + s];
                out[O10 + fidx + k] = iv;
            }
        }
    }
}

extern "C" void kernel_launch(void* const* d_in, const int* in_sizes, int n_in,
                              void* d_out, int out_size, void* d_ws, size_t ws_size,
                              hipStream_t stream) {
    const float* r      = (const float*)d_in[0];
    const int*   x      = (const int*)d_in[1];
    const float* Kin    = (const float*)d_in[2];
    const float* Vin    = (const float*)d_in[3];
    const int*   Iin    = (const int*)d_in[5];
    const int*   t_ptr  = (const int*)d_in[6];
    const float* eps_q  = (const float*)d_in[7];
    const float* eps_k  = (const float*)d_in[8];
    const float* eps_v  = (const float*)d_in[9];
    const float* eps_z  = (const float*)d_in[10];
    const float* gumbel = (const float*)d_in[11];
    const float* Wq = (const float*)d_in[12]; const float* bq = (const float*)d_in[13];
    const float* Wk = (const float*)d_in[14]; const float* bk = (const float*)d_in[15];
    const float* Wv = (const float*)d_in[16]; const float* bv = (const float*)d_in[17];
    const float* Wo = (const float*)d_in[18]; const float* bo = (const float*)d_in[19];
    const float* ln1_g = (const float*)d_in[20]; const float* ln1_b = (const float*)d_in[21];
    const float* ln3_g = (const float*)d_in[22]; const float* ln3_b = (const float*)d_in[23];
    const float* W1 = (const float*)d_in[24]; const float* b1 = (const float*)d_in[25];
    const float* W2 = (const float*)d_in[26]; const float* b2 = (const float*)d_in[27];
    const float* Wout = (const float*)d_in[28]; const float* bout = (const float*)d_in[29];

    float* ws  = (float*)d_ws;
    float* q   = ws + WQ;
    float* kv  = ws + WK;
    float* vv  = ws + WV;
    float* zh  = ws + WZH;
    float* zp  = ws + WZ;
    float* o1  = ws + WO1;
    float* h1  = ws + WH1;
    float* pr  = ws + WPRED;
    float* rmx = ws + WMAX;
    float* rsm = ws + WSUM;
    float* wsq = ws + WWSQ;
    int*   itw = (int*)(ws + WIT);
    float* f2p = ws + WF2P;
    float* scw = ws + WSC;
    float* outp = (float*)d_out;

    k_qkv<<<dim3(8, 16, 3), 512, 0, stream>>>(r, Wq, bq, eps_q, q, Wk, bk, eps_k, kv, Wv, bv, eps_v, vv);
    k_attn<<<dim3(128, 8), 512, 0, stream>>>(q, kv, vv, Kin, Vin, t_ptr, zh, scw);
    k_zproj<<<dim3(12, 16), 512, 0, stream>>>(zh, Wo, bo, eps_z, Kin, t_ptr, outp, zp);
    k_ffn1<<<dim3(36, 16), 512, 0, stream>>>(zp, r, ln1_g, ln1_b, W1, b1, Kin, t_ptr, outp, o1, h1);
    k_ffn2p<<<dim3(9, 16, 4), 512, 0, stream>>>(h1, W2, Kin, t_ptr, outp, f2p);
    k_pred<<<dim3(48, 8), 512, 0, stream>>>(f2p, b2, o1, ln3_g, ln3_b, Wout, bout, Kin, t_ptr, outp, pr);
    k_soft<<<128, 512, 0, stream>>>(pr, x, scw, t_ptr, rmx, rsm, wsq, outp);
    k_vocab<<<dim3(20, 8), 512, 0, stream>>>(pr, rmx, rsm, wsq, gumbel, itw, outp);
    k_resample<<<2048, 256, 0, stream>>>(Kin, kv, itw, t_ptr, r, eps_z, zp, Iin, outp);
}

// Round 10
// 218.432 us; speedup vs baseline: 1.0649x; 1.0649x over previous
//
#include <hip/hip_runtime.h>

#define NDFF 2048
#define NVOC 10000
#define SIGMA 0.1f

typedef float f32x4 __attribute__((ext_vector_type(4)));

// ---- output offsets (floats) ----
#define O0 0
#define O1 65536
#define O2 131072
#define O3 211072
#define O4 291072
#define O5 371072
#define O6 436608
#define O7 502144
#define O8 34056576
#define O9 67611008
#define O10 67611136

// ---- workspace offsets (floats) ----
#define WQ    0
#define WK    65536
#define WV    131072
#define WZH   196608
#define WZ    262144
#define WO1   327680
#define WH1   393216
#define WPRED 720896
#define WMAX  2000896
#define WSUM  2001024
#define WWSQ  2001152
#define WIT   2001280
#define WF2P  2001536
#define WSC   2263680

// ===== QKV projection. grid (8, 16, 3), 512 thr; 8-way K-split =====
__global__ __launch_bounds__(512)
void k_qkv(const float* __restrict__ r,
           const float* __restrict__ Wq, const float* __restrict__ bq, const float* __restrict__ eq, float* __restrict__ oq,
           const float* __restrict__ Wk, const float* __restrict__ bk, const float* __restrict__ ek, float* __restrict__ ok,
           const float* __restrict__ Wv, const float* __restrict__ bv, const float* __restrict__ ev, float* __restrict__ ov)
{
    const float *W, *bias, *eps; float* out;
    if (blockIdx.z == 0)      { W = Wq; bias = bq; eps = eq; out = oq; }
    else if (blockIdx.z == 1) { W = Wk; bias = bk; eps = ek; out = ok; }
    else                      { W = Wv; bias = bv; eps = ev; out = ov; }
    int tid = threadIdx.x;
    int col = tid & 63, kq = tid >> 6;
    int colg = blockIdx.x * 64 + col;
    int row0 = blockIdx.y * 8;
    __shared__ float rs[8][512];
#pragma unroll
    for (int j = 0; j < 8; j++) rs[j][tid & 511] = r[(row0 + j) * 512 + tid];
    __syncthreads();
    float acc[8] = {0,0,0,0,0,0,0,0};
    const float* Wp = W + (kq * 64) * 512 + colg;
#pragma unroll 8
    for (int d = 0; d < 64; d++) {
        float wv = Wp[d * 512];
#pragma unroll
        for (int p = 0; p < 8; p++) acc[p] += rs[p][kq * 64 + d] * wv;
    }
    __syncthreads();
    float (*part)[8][64] = (float(*)[8][64])rs;
#pragma unroll
    for (int p = 0; p < 8; p++) part[kq][p][col] = acc[p];
    __syncthreads();
    {
        int p = tid >> 6, c = tid & 63;
        int cg = blockIdx.x * 64 + c;
        float v = 0.f;
#pragma unroll
        for (int k = 0; k < 8; k++) v += part[k][p][c];
        out[(row0 + p) * 512 + cg] = v + bias[cg] + SIGMA * eps[(row0 + p) * 512 + cg];
    }
}

// ===== fused attention + s>t K/Vs copy. grid (160, 8), 512 thr =====
// blocks x<128: attention per (bp, h). blocks x>=128: 256 copy blocks.
__global__ __launch_bounds__(512)
void k_attn(const float* __restrict__ qws, const float* __restrict__ kws,
            const float* __restrict__ vws, const float* __restrict__ Kin,
            const float* __restrict__ Vin, const int* __restrict__ t_ptr,
            float* __restrict__ zh, float* __restrict__ scw,
            float* __restrict__ outfull)
{
    int t = *t_ptr;
    if (blockIdx.x >= 128) {
        // s>t copy: K_out = Vs_out = Kin for s in (t, 511]
        int bid = (blockIdx.x - 128) * 8 + blockIdx.y;   // 0..255
        int tid = threadIdx.x;
        const f32x4* K4 = (const f32x4*)Kin;
        f32x4* oK = (f32x4*)(outfull + O7);
        f32x4* oV = (f32x4*)(outfull + O8);
        int cnt = 511 - t;
        long totalc = (long)128 * cnt * 128;
        for (long j = (long)bid * 512 + tid; j < totalc; j += (long)256 * 512) {
            int lane = (int)(j & 127);
            long row = j >> 7;                 // bp*cnt + (s - t - 1)
            int bp = (int)(row / cnt);
            int s = t + 1 + (int)(row - (long)bp * cnt);
            long i = ((long)(bp * 512 + s) << 7) + lane;
            f32x4 v = __builtin_nontemporal_load(&K4[i]);
            __builtin_nontemporal_store(v, &oK[i]);
            __builtin_nontemporal_store(v, &oV[i]);
        }
        return;
    }
    int bp = blockIdx.x, h = blockIdx.y;
    int tid = threadIdx.x;
    int wave = tid >> 6, lane = tid & 63;
    __shared__ float sc[512];
    __shared__ float red[8], red2[8];
    __shared__ float part[8][64];

    float4 qv = ((const float4*)(qws + bp * 512 + h * 64))[lane & 15];

    for (int sb = wave * 4; sb <= t; sb += 32) {
        int s = sb + (lane >> 4);
        bool valid = (s <= t);
        int ss = valid ? s : t;
        const float4* kr = (ss == t) ? (const float4*)(kws + bp * 512 + h * 64)
                                     : (const float4*)(Kin + (bp * 512 + ss) * 512 + h * 64);
        float4 kv = kr[lane & 15];
        float p = qv.x * kv.x + qv.y * kv.y + qv.z * kv.z + qv.w * kv.w;
#pragma unroll
        for (int m = 1; m < 16; m <<= 1) p += __shfl_xor(p, m, 64);
        if ((lane & 15) == 0 && valid) sc[s] = p * 0.125f;
    }
    __syncthreads();

    float lm = -3.0e38f;
    for (int s = tid; s <= t; s += 512) lm = fmaxf(lm, sc[s]);
#pragma unroll
    for (int o = 32; o; o >>= 1) lm = fmaxf(lm, __shfl_xor(lm, o, 64));
    if (lane == 0) red[wave] = lm;
    __syncthreads();
    float m = red[0];
#pragma unroll
    for (int i = 1; i < 8; i++) m = fmaxf(m, red[i]);
    float ls = 0.f;
    for (int s = tid; s <= t; s += 512) ls += __expf(sc[s] - m);
#pragma unroll
    for (int o = 32; o; o >>= 1) ls += __shfl_xor(ls, o, 64);
    if (lane == 0) red2[wave] = ls;
    __syncthreads();
    float tot = 0.f;
#pragma unroll
    for (int i = 0; i < 8; i++) tot += red2[i];
    float inv = 1.f / tot;
    for (int s = tid; s <= t; s += 512) {
        float a = __expf(sc[s] - m) * inv;
        sc[s] = a;
        scw[(bp * 8 + h) * 512 + s] = a;
    }
    __syncthreads();

    float acc = 0.f;
    const float* Vp = Vin + (bp * 512) * 512 + h * 64 + lane;
    int s = wave;
    for (; s + 24 < t; s += 32) {
        float v0 = __builtin_nontemporal_load(Vp + (size_t)(s     ) * 512);
        float v1 = __builtin_nontemporal_load(Vp + (size_t)(s +  8) * 512);
        float v2 = __builtin_nontemporal_load(Vp + (size_t)(s + 16) * 512);
        float v3 = __builtin_nontemporal_load(Vp + (size_t)(s + 24) * 512);
        acc += sc[s] * v0 + sc[s + 8] * v1 + sc[s + 16] * v2 + sc[s + 24] * v3;
    }
    for (; s < t; s += 8) acc += sc[s] * __builtin_nontemporal_load(Vp + (size_t)s * 512);
    if ((t & 7) == wave) acc += sc[t] * vws[bp * 512 + h * 64 + lane];
    part[wave][lane] = acc;
    __syncthreads();
    if (tid < 64) {
        float v = 0.f;
#pragma unroll
        for (int k = 0; k < 8; k++) v += part[k][tid];
        zh[bp * 512 + h * 64 + tid] = v;
    }
}

// ===== z projection. grid (8, 16), 512 thr; 8-way K-split =====
__global__ __launch_bounds__(512)
void k_zproj(const float* __restrict__ zh, const float* __restrict__ Wo,
             const float* __restrict__ bo, const float* __restrict__ epsz,
             float* __restrict__ out)
{
    int tid = threadIdx.x;
    int col = tid & 63, kq = tid >> 6;
    int colg = blockIdx.x * 64 + col;
    int row0 = blockIdx.y * 8;
    __shared__ float rs[8][512];
#pragma unroll
    for (int j = 0; j < 8; j++) rs[j][tid] = zh[(row0 + j) * 512 + tid];
    __syncthreads();
    float acc[8] = {0,0,0,0,0,0,0,0};
    const float* Wp = Wo + (kq * 64) * 512 + colg;
#pragma unroll 8
    for (int d = 0; d < 64; d++) {
        float wv = Wp[d * 512];
#pragma unroll
        for (int p = 0; p < 8; p++) acc[p] += rs[p][kq * 64 + d] * wv;
    }
    __syncthreads();
    float (*part)[8][64] = (float(*)[8][64])rs;
#pragma unroll
    for (int p = 0; p < 8; p++) part[kq][p][col] = acc[p];
    __syncthreads();
    {
        int p = tid >> 6, c = tid & 63;
        int cg = blockIdx.x * 64 + c;
        float v = 0.f;
#pragma unroll
        for (int k = 0; k < 8; k++) v += part[k][p][c];
        out[(row0 + p) * 512 + cg] = v + bo[cg] + SIGMA * epsz[(row0 + p) * 512 + cg];
    }
}

// ===== ffn1 + fused LN1. grid (32, 16), 512 thr; 8-way K-split =====
__global__ __launch_bounds__(512)
void k_ffn1(const float* __restrict__ zp, const float* __restrict__ r,
            const float* __restrict__ g, const float* __restrict__ be,
            const float* __restrict__ W1, const float* __restrict__ b1,
            float* __restrict__ o1, float* __restrict__ h1)
{
    int tid = threadIdx.x;
    int col = tid & 63, kq = tid >> 6;
    int colg = blockIdx.x * 64 + col;
    int row0 = blockIdx.y * 8;
    __shared__ float rs[8][512];
    __shared__ float sm[8], si[8];
    int wave = tid >> 6, lane = tid & 63;
#pragma unroll
    for (int j = 0; j < 8; j++) {
        int gi = (row0 + j) * 512 + tid;
        rs[j][tid] = zp[gi] + r[gi];
    }
    __syncthreads();
    {
        float s = 0.f;
        for (int c = lane; c < 512; c += 64) s += rs[wave][c];
#pragma unroll
        for (int o = 32; o; o >>= 1) s += __shfl_xor(s, o, 64);
        float mu = s * (1.f / 512.f);
        float v = 0.f;
        for (int c = lane; c < 512; c += 64) { float dx = rs[wave][c] - mu; v += dx * dx; }
#pragma unroll
        for (int o = 32; o; o >>= 1) v += __shfl_xor(v, o, 64);
        if (lane == 0) { sm[wave] = mu; si[wave] = rsqrtf(v * (1.f / 512.f) + 1e-6f); }
    }
    __syncthreads();
#pragma unroll
    for (int j = 0; j < 8; j++) {
        float val = (rs[j][tid] - sm[j]) * si[j] * g[tid] + be[tid];
        rs[j][tid] = val;
        if (blockIdx.x == 0) o1[(row0 + j) * 512 + tid] = val;
    }
    __syncthreads();
    float acc[8] = {0,0,0,0,0,0,0,0};
    const float* Wp = W1 + (kq * 64) * NDFF + colg;
#pragma unroll 8
    for (int d = 0; d < 64; d++) {
        float wv = Wp[d * NDFF];
#pragma unroll
        for (int p = 0; p < 8; p++) acc[p] += rs[p][kq * 64 + d] * wv;
    }
    __syncthreads();
    float (*part)[8][64] = (float(*)[8][64])rs;
#pragma unroll
    for (int p = 0; p < 8; p++) part[kq][p][col] = acc[p];
    __syncthreads();
    {
        int p = tid >> 6, c = tid & 63;
        int cg = blockIdx.x * 64 + c;
        float v = 0.f;
#pragma unroll
        for (int k = 0; k < 8; k++) v += part[k][p][c];
        h1[(row0 + p) * NDFF + cg] = fmaxf(v + b1[cg], 0.f);
    }
}

// ===== ffn2 partials. grid (8, 16, 4), 512 thr =====
__global__ __launch_bounds__(512)
void k_ffn2p(const float* __restrict__ h1, const float* __restrict__ W2,
             float* __restrict__ f2p)
{
    int tid = threadIdx.x;
    int col = tid & 63, kq = tid >> 6;
    int colg = blockIdx.x * 64 + col;
    int row0 = blockIdx.y * 8;
    int ks = blockIdx.z;
    __shared__ float rs[8][512];
#pragma unroll
    for (int j = 0; j < 8; j++)
        rs[j][tid] = h1[(row0 + j) * NDFF + ks * 512 + tid];
    __syncthreads();
    float acc[8] = {0,0,0,0,0,0,0,0};
    const float* Wp = W2 + (ks * 512 + kq * 64) * 512 + colg;
#pragma unroll 8
    for (int d = 0; d < 64; d++) {
        float wv = Wp[d * 512];
#pragma unroll
        for (int p = 0; p < 8; p++) acc[p] += rs[p][kq * 64 + d] * wv;
    }
    __syncthreads();
    float (*part)[8][64] = (float(*)[8][64])rs;
#pragma unroll
    for (int p = 0; p < 8; p++) part[kq][p][col] = acc[p];
    __syncthreads();
    {
        int p = tid >> 6, c = tid & 63;
        int cg = blockIdx.x * 64 + c;
        float v = 0.f;
#pragma unroll
        for (int k = 0; k < 8; k++) v += part[k][p][c];
        f2p[ks * 65536 + (row0 + p) * 512 + cg] = v;
    }
}

// ===== pred + fused LN3. grid (40, 8), 512 thr; 2-way K-split =====
__global__ __launch_bounds__(512)
void k_pred(const float* __restrict__ f2p, const float* __restrict__ b2,
            const float* __restrict__ o1, const float* __restrict__ g3,
            const float* __restrict__ b3, const float* __restrict__ Wout,
            const float* __restrict__ bout, float* __restrict__ pred)
{
    int tid = threadIdx.x;
    int col = tid & 255, kh = tid >> 8;
    int colg = blockIdx.x * 256 + col;
    int colL = min(colg, NVOC - 1);
    int row0 = blockIdx.y * 16;
    __shared__ float rs[16][512];
    __shared__ float sm[16], si[16];
    int wave = tid >> 6, lane = tid & 63;
#pragma unroll
    for (int j = 0; j < 16; j++) {
        int gi = (row0 + j) * 512 + tid;
        rs[j][tid] = f2p[gi] + f2p[65536 + gi] + f2p[131072 + gi] + f2p[196608 + gi]
                   + b2[tid] + o1[gi];
    }
    __syncthreads();
    {
        int row = wave * 2 + (lane >> 5);
        int l = lane & 31;
        float s = 0.f;
        for (int c = l; c < 512; c += 32) s += rs[row][c];
#pragma unroll
        for (int o = 16; o; o >>= 1) s += __shfl_xor(s, o, 64);
        float mu = s * (1.f / 512.f);
        float v = 0.f;
        for (int c = l; c < 512; c += 32) { float dx = rs[row][c] - mu; v += dx * dx; }
#pragma unroll
        for (int o = 16; o; o >>= 1) v += __shfl_xor(v, o, 64);
        if (l == 0) { sm[row] = mu; si[row] = rsqrtf(v * (1.f / 512.f) + 1e-6f); }
    }
    __syncthreads();
#pragma unroll
    for (int j = 0; j < 16; j++)
        rs[j][tid] = (rs[j][tid] - sm[j]) * si[j] * g3[tid] + b3[tid];
    __syncthreads();
    float acc[16];
#pragma unroll
    for (int p = 0; p < 16; p++) acc[p] = 0.f;
    const float* Wp = Wout + (kh * 256) * NVOC + colL;
#pragma unroll 4
    for (int d = 0; d < 256; d++) {
        float wv = Wp[d * NVOC];
#pragma unroll
        for (int p = 0; p < 16; p++) acc[p] += rs[p][kh * 256 + d] * wv;
    }
    __syncthreads();
    float (*part)[256] = (float(*)[256])rs;
    if (kh == 1) {
#pragma unroll
        for (int p = 0; p < 16; p++) part[p][col] = acc[p];
    }
    __syncthreads();
    if (kh == 0 && colg < NVOC) {
        float bv = bout[colg];
#pragma unroll
        for (int p = 0; p < 16; p++)
            pred[(row0 + p) * NVOC + colg] = acc[p] + part[p][col] + bv;
    }
}

// ===== per-row softmax stats + w_sq + attn_weights. grid 128, 512 thr =====
__global__ __launch_bounds__(512)
void k_soft(const float* __restrict__ pred, const int* __restrict__ x,
            const float* __restrict__ scw, const int* __restrict__ t_ptr,
            float* __restrict__ rowmax, float* __restrict__ rowsum,
            float* __restrict__ wsq, float* __restrict__ out)
{
    __shared__ float red[8];
    int row = blockIdx.x, tid = threadIdx.x;
    {
        int t = *t_ptr;
        float a = 0.f;
        if (tid <= t) {
#pragma unroll
            for (int hh = 0; hh < 8; hh++) a += scw[(row * 8 + hh) * 512 + tid];
            a *= 0.125f;
        }
        out[O6 + row * 512 + tid] = a;
    }
    const float* pr = pred + row * NVOC;
    float m = -3.0e38f;
    for (int v = tid; v < NVOC; v += 512) m = fmaxf(m, pr[v]);
#pragma unroll
    for (int o = 32; o; o >>= 1) m = fmaxf(m, __shfl_xor(m, o, 64));
    if ((tid & 63) == 0) red[tid >> 6] = m;
    __syncthreads();
#pragma unroll
    for (int i = 0; i < 8; i++) m = fmaxf(m, red[i]);
    __syncthreads();
    float s = 0.f;
    for (int v = tid; v < NVOC; v += 512) s += __expf(pr[v] - m);
#pragma unroll
    for (int o = 32; o; o >>= 1) s += __shfl_xor(s, o, 64);
    if ((tid & 63) == 0) red[tid >> 6] = s;
    __syncthreads();
    if (tid == 0) {
        float tot = 0.f;
#pragma unroll
        for (int i = 0; i < 8; i++) tot += red[i];
        rowmax[row] = m; rowsum[row] = tot;
        int b = row >> 4;
        float w = __expf(pr[x[b]] - m) / tot;
        wsq[row] = w;
        out[O9 + row] = w;
    }
}

// ===== vocab outputs + it/amw. grid (20, 8), 512 thr =====
__global__ __launch_bounds__(512)
void k_vocab(const float* __restrict__ pred, const float* __restrict__ rowmax,
             const float* __restrict__ rowsum, const float* __restrict__ wsq,
             const float* __restrict__ gumbel, int* __restrict__ it,
             float* __restrict__ out)
{
    int b = blockIdx.y;
    int tid = threadIdx.x;
    __shared__ int s_amw;
    if (tid == 0) {
        float bw = -3.0e38f; int bj = 0;
#pragma unroll
        for (int pp = 0; pp < 16; pp++) {
            float wv = wsq[b * 16 + pp];
            if (wv > bw) { bw = wv; bj = pp; }
        }
        s_amw = bj;
    }
    if (blockIdx.x == 0 && tid < 16) {
        float best = -3.0e38f; int bi = 0;
#pragma unroll
        for (int pp = 0; pp < 16; pp++) {
            float v = logf(wsq[b * 16 + pp] + 1e-10f) + gumbel[(b * 16 + tid) * 16 + pp];
            if (v > best) { best = v; bi = pp; }
        }
        it[b * 16 + tid] = bi;
    }
    __syncthreads();
    int v = blockIdx.x * 512 + tid;
    if (v >= NVOC) return;
    int amw = s_amw;
    float ga = 0.f, as = 0.f;
#pragma unroll
    for (int p = 0; p < 16; p++) {
        int rr = b * 16 + p;
        float pv = pred[rr * NVOC + v];
        ga += pv;
        as += __expf(pv - rowmax[rr]) * (1.f / rowsum[rr]);
    }
    out[O3 + b * NVOC + v] = ga * (1.f / 16.f);
    out[O2 + b * NVOC + v] = as * (1.f / 16.f);
    out[O4 + b * NVOC + v] = pred[(b * 16 + amw) * NVOC + v];
}

// ===== K / Vs gather (s<=t only) + misc outputs. grid 2048 x 256 =====
__global__ __launch_bounds__(256)
void k_resample(const float* __restrict__ Kin, const float* __restrict__ kws,
                const int* __restrict__ it, const int* __restrict__ t_ptr,
                const float* __restrict__ r, const float* __restrict__ epsz,
                const float* __restrict__ zws, const int* __restrict__ Iin,
                float* __restrict__ out)
{
    int t = *t_ptr;
    const f32x4* K4  = (const f32x4*)Kin;
    const f32x4* kw4 = (const f32x4*)kws;
    const f32x4* r4  = (const f32x4*)r;
    const f32x4* e4  = (const f32x4*)epsz;
    const f32x4* z4  = (const f32x4*)zws;
    f32x4* oK = (f32x4*)(out + O7);
    f32x4* oV = (f32x4*)(out + O8);
    int cnt = t + 1;
    long total = (long)128 * cnt * 128;
    long total2 = total + 16384;
    for (long j = (long)blockIdx.x * 256 + threadIdx.x; j < total2; j += (long)gridDim.x * 256) {
        if (j < total) {
            int lane = (int)(j & 127);
            long row = j >> 7;              // bp*cnt + s
            int bp = (int)(row / cnt);
            int s = (int)(row - (long)bp * cnt);
            int b = bp >> 4;
            int ip = it[bp];
            int ip2 = it[b * 16 + ip];
            f32x4 vK, vV;
            if (s == t) {
                vK = kw4[(b * 16 + ip) * 128 + lane];
                vV = kw4[(b * 16 + ip2) * 128 + lane];
            } else {
                vK = K4[((long)((b * 16 + ip) * 512 + s) << 7) + lane];
                vV = K4[((long)((b * 16 + ip2) * 512 + s) << 7) + lane];
            }
            long i = ((long)(bp * 512 + s) << 7) + lane;
            __builtin_nontemporal_store(vK, &oK[i]);
            __builtin_nontemporal_store(vV, &oV[i]);
        } else {
            int jj = (int)(j - total);
            int fidx = jj * 4;
            ((f32x4*)(out + O0))[jj] = r4[jj];
            ((f32x4*)(out + O5))[jj] = e4[jj];
            int row = fidx >> 9, d0 = fidx & 511;
            int b = row >> 4;
            int ip = it[row];
            ((f32x4*)(out + O1))[jj] = z4[((b * 16 + ip) << 7) + (d0 >> 2)];
#pragma unroll
            for (int k = 0; k < 4; k++) {
                int s = d0 + k;
                float iv;
                if (s < t)       iv = (float)Iin[((b * 16 + ip) << 9) + s];
                else if (s == t) iv = (float)ip;
                else             iv = (float)Iin[row * 512 + s];
                out[O10 + fidx + k] = iv;
            }
        }
    }
}

extern "C" void kernel_launch(void* const* d_in, const int* in_sizes, int n_in,
                              void* d_out, int out_size, void* d_ws, size_t ws_size,
                              hipStream_t stream) {
    const float* r      = (const float*)d_in[0];
    const int*   x      = (const int*)d_in[1];
    const float* Kin    = (const float*)d_in[2];
    const float* Vin    = (const float*)d_in[3];
    const int*   Iin    = (const int*)d_in[5];
    const int*   t_ptr  = (const int*)d_in[6];
    const float* eps_q  = (const float*)d_in[7];
    const float* eps_k  = (const float*)d_in[8];
    const float* eps_v  = (const float*)d_in[9];
    const float* eps_z  = (const float*)d_in[10];
    const float* gumbel = (const float*)d_in[11];
    const float* Wq = (const float*)d_in[12]; const float* bq = (const float*)d_in[13];
    const float* Wk = (const float*)d_in[14]; const float* bk = (const float*)d_in[15];
    const float* Wv = (const float*)d_in[16]; const float* bv = (const float*)d_in[17];
    const float* Wo = (const float*)d_in[18]; const float* bo = (const float*)d_in[19];
    const float* ln1_g = (const float*)d_in[20]; const float* ln1_b = (const float*)d_in[21];
    const float* ln3_g = (const float*)d_in[22]; const float* ln3_b = (const float*)d_in[23];
    const float* W1 = (const float*)d_in[24]; const float* b1 = (const float*)d_in[25];
    const float* W2 = (const float*)d_in[26]; const float* b2 = (const float*)d_in[27];
    const float* Wout = (const float*)d_in[28]; const float* bout = (const float*)d_in[29];

    float* ws  = (float*)d_ws;
    float* q   = ws + WQ;
    float* kv  = ws + WK;
    float* vv  = ws + WV;
    float* zh  = ws + WZH;
    float* zp  = ws + WZ;
    float* o1  = ws + WO1;
    float* h1  = ws + WH1;
    float* pr  = ws + WPRED;
    float* rmx = ws + WMAX;
    float* rsm = ws + WSUM;
    float* wsq = ws + WWSQ;
    int*   itw = (int*)(ws + WIT);
    float* f2p = ws + WF2P;
    float* scw = ws + WSC;
    float* outp = (float*)d_out;

    k_qkv<<<dim3(8, 16, 3), 512, 0, stream>>>(r, Wq, bq, eps_q, q, Wk, bk, eps_k, kv, Wv, bv, eps_v, vv);
    k_attn<<<dim3(160, 8), 512, 0, stream>>>(q, kv, vv, Kin, Vin, t_ptr, zh, scw, outp);
    k_zproj<<<dim3(8, 16), 512, 0, stream>>>(zh, Wo, bo, eps_z, zp);
    k_ffn1<<<dim3(32, 16), 512, 0, stream>>>(zp, r, ln1_g, ln1_b, W1, b1, o1, h1);
    k_ffn2p<<<dim3(8, 16, 4), 512, 0, stream>>>(h1, W2, f2p);
    k_pred<<<dim3(40, 8), 512, 0, stream>>>(f2p, b2, o1, ln3_g, ln3_b, Wout, bout, pr);
    k_soft<<<128, 512, 0, stream>>>(pr, x, scw, t_ptr, rmx, rsm, wsq, outp);
    k_vocab<<<dim3(20, 8), 512, 0, stream>>>(pr, rmx, rsm, wsq, gumbel, itw, outp);
    k_resample<<<2048, 256, 0, stream>>>(Kin, kv, itw, t_ptr, r, eps_z, zp, Iin, outp);
}

// Round 11
// 199.614 us; speedup vs baseline: 1.1653x; 1.0943x over previous
//
#include <hip/hip_runtime.h>

#define NDFF 2048
#define NVOC 10000
#define SIGMA 0.1f

typedef float f32x4 __attribute__((ext_vector_type(4)));

// ---- output offsets (floats) ----
#define O0 0
#define O1 65536
#define O2 131072
#define O3 211072
#define O4 291072
#define O5 371072
#define O6 436608
#define O7 502144
#define O8 34056576
#define O9 67611008
#define O10 67611136

// ---- workspace offsets (floats) ----
#define WQ    0
#define WK    65536
#define WV    131072
#define WZH   196608
#define WZ    262144
#define WO1   327680
#define WH1   393216
#define WPRED 720896
#define WMAX  2000896
#define WSUM  2001024
#define WWSQ  2001152
#define WIT   2001280
#define WF2P  2001536
#define WSC   2263680

// ===== QKV projection. grid (8, 16, 3), 512 thr; 8-way K-split =====
__global__ __launch_bounds__(512)
void k_qkv(const float* __restrict__ r,
           const float* __restrict__ Wq, const float* __restrict__ bq, const float* __restrict__ eq, float* __restrict__ oq,
           const float* __restrict__ Wk, const float* __restrict__ bk, const float* __restrict__ ek, float* __restrict__ ok,
           const float* __restrict__ Wv, const float* __restrict__ bv, const float* __restrict__ ev, float* __restrict__ ov)
{
    const float *W, *bias, *eps; float* out;
    if (blockIdx.z == 0)      { W = Wq; bias = bq; eps = eq; out = oq; }
    else if (blockIdx.z == 1) { W = Wk; bias = bk; eps = ek; out = ok; }
    else                      { W = Wv; bias = bv; eps = ev; out = ov; }
    int tid = threadIdx.x;
    int col = tid & 63, kq = tid >> 6;
    int colg = blockIdx.x * 64 + col;
    int row0 = blockIdx.y * 8;
    __shared__ float rs[8][512];
#pragma unroll
    for (int j = 0; j < 8; j++) rs[j][tid & 511] = r[(row0 + j) * 512 + tid];
    __syncthreads();
    float acc[8] = {0,0,0,0,0,0,0,0};
    const float* Wp = W + (kq * 64) * 512 + colg;
#pragma unroll 8
    for (int d = 0; d < 64; d++) {
        float wv = Wp[d * 512];
#pragma unroll
        for (int p = 0; p < 8; p++) acc[p] += rs[p][kq * 64 + d] * wv;
    }
    __syncthreads();
    float (*part)[8][64] = (float(*)[8][64])rs;
#pragma unroll
    for (int p = 0; p < 8; p++) part[kq][p][col] = acc[p];
    __syncthreads();
    {
        int p = tid >> 6, c = tid & 63;
        int cg = blockIdx.x * 64 + c;
        float v = 0.f;
#pragma unroll
        for (int k = 0; k < 8; k++) v += part[k][p][c];
        out[(row0 + p) * 512 + cg] = v + bias[cg] + SIGMA * eps[(row0 + p) * 512 + cg];
    }
}

// ===== fused attention. grid (128, 8), 512 thr =====
__global__ __launch_bounds__(512)
void k_attn(const float* __restrict__ qws, const float* __restrict__ kws,
            const float* __restrict__ vws, const float* __restrict__ Kin,
            const float* __restrict__ Vin, const int* __restrict__ t_ptr,
            float* __restrict__ zh, float* __restrict__ scw)
{
    int t = *t_ptr;
    int bp = blockIdx.x, h = blockIdx.y;
    int tid = threadIdx.x;
    int wave = tid >> 6, lane = tid & 63;
    __shared__ float sc[512];
    __shared__ float red[8], red2[8];
    __shared__ float part[8][64];

    float4 qv = ((const float4*)(qws + bp * 512 + h * 64))[lane & 15];

    for (int sb = wave * 4; sb <= t; sb += 32) {
        int s = sb + (lane >> 4);
        bool valid = (s <= t);
        int ss = valid ? s : t;
        const float4* kr = (ss == t) ? (const float4*)(kws + bp * 512 + h * 64)
                                     : (const float4*)(Kin + (bp * 512 + ss) * 512 + h * 64);
        float4 kv = kr[lane & 15];
        float p = qv.x * kv.x + qv.y * kv.y + qv.z * kv.z + qv.w * kv.w;
#pragma unroll
        for (int m = 1; m < 16; m <<= 1) p += __shfl_xor(p, m, 64);
        if ((lane & 15) == 0 && valid) sc[s] = p * 0.125f;
    }
    __syncthreads();

    float lm = -3.0e38f;
    for (int s = tid; s <= t; s += 512) lm = fmaxf(lm, sc[s]);
#pragma unroll
    for (int o = 32; o; o >>= 1) lm = fmaxf(lm, __shfl_xor(lm, o, 64));
    if (lane == 0) red[wave] = lm;
    __syncthreads();
    float m = red[0];
#pragma unroll
    for (int i = 1; i < 8; i++) m = fmaxf(m, red[i]);
    float ls = 0.f;
    for (int s = tid; s <= t; s += 512) ls += __expf(sc[s] - m);
#pragma unroll
    for (int o = 32; o; o >>= 1) ls += __shfl_xor(ls, o, 64);
    if (lane == 0) red2[wave] = ls;
    __syncthreads();
    float tot = 0.f;
#pragma unroll
    for (int i = 0; i < 8; i++) tot += red2[i];
    float inv = 1.f / tot;
    for (int s = tid; s <= t; s += 512) {
        float a = __expf(sc[s] - m) * inv;
        sc[s] = a;
        scw[(bp * 8 + h) * 512 + s] = a;
    }
    __syncthreads();

    float acc = 0.f;
    const float* Vp = Vin + (bp * 512) * 512 + h * 64 + lane;
    int s = wave;
    for (; s + 24 < t; s += 32) {
        float v0 = __builtin_nontemporal_load(Vp + (size_t)(s     ) * 512);
        float v1 = __builtin_nontemporal_load(Vp + (size_t)(s +  8) * 512);
        float v2 = __builtin_nontemporal_load(Vp + (size_t)(s + 16) * 512);
        float v3 = __builtin_nontemporal_load(Vp + (size_t)(s + 24) * 512);
        acc += sc[s] * v0 + sc[s + 8] * v1 + sc[s + 16] * v2 + sc[s + 24] * v3;
    }
    for (; s < t; s += 8) acc += sc[s] * __builtin_nontemporal_load(Vp + (size_t)s * 512);
    if ((t & 7) == wave) acc += sc[t] * vws[bp * 512 + h * 64 + lane];
    part[wave][lane] = acc;
    __syncthreads();
    if (tid < 64) {
        float v = 0.f;
#pragma unroll
        for (int k = 0; k < 8; k++) v += part[k][tid];
        zh[bp * 512 + h * 64 + tid] = v;
    }
}

// ===== z projection. grid (8, 16), 512 thr; 8-way K-split =====
__global__ __launch_bounds__(512)
void k_zproj(const float* __restrict__ zh, const float* __restrict__ Wo,
             const float* __restrict__ bo, const float* __restrict__ epsz,
             float* __restrict__ out)
{
    int tid = threadIdx.x;
    int col = tid & 63, kq = tid >> 6;
    int colg = blockIdx.x * 64 + col;
    int row0 = blockIdx.y * 8;
    __shared__ float rs[8][512];
#pragma unroll
    for (int j = 0; j < 8; j++) rs[j][tid] = zh[(row0 + j) * 512 + tid];
    __syncthreads();
    float acc[8] = {0,0,0,0,0,0,0,0};
    const float* Wp = Wo + (kq * 64) * 512 + colg;
#pragma unroll 8
    for (int d = 0; d < 64; d++) {
        float wv = Wp[d * 512];
#pragma unroll
        for (int p = 0; p < 8; p++) acc[p] += rs[p][kq * 64 + d] * wv;
    }
    __syncthreads();
    float (*part)[8][64] = (float(*)[8][64])rs;
#pragma unroll
    for (int p = 0; p < 8; p++) part[kq][p][col] = acc[p];
    __syncthreads();
    {
        int p = tid >> 6, c = tid & 63;
        int cg = blockIdx.x * 64 + c;
        float v = 0.f;
#pragma unroll
        for (int k = 0; k < 8; k++) v += part[k][p][c];
        out[(row0 + p) * 512 + cg] = v + bo[cg] + SIGMA * epsz[(row0 + p) * 512 + cg];
    }
}

// ===== ffn1 + fused LN1. grid (32, 16), 512 thr; 8-way K-split =====
__global__ __launch_bounds__(512)
void k_ffn1(const float* __restrict__ zp, const float* __restrict__ r,
            const float* __restrict__ g, const float* __restrict__ be,
            const float* __restrict__ W1, const float* __restrict__ b1,
            float* __restrict__ o1, float* __restrict__ h1)
{
    int tid = threadIdx.x;
    int col = tid & 63, kq = tid >> 6;
    int colg = blockIdx.x * 64 + col;
    int row0 = blockIdx.y * 8;
    __shared__ float rs[8][512];
    __shared__ float sm[8], si[8];
    int wave = tid >> 6, lane = tid & 63;
#pragma unroll
    for (int j = 0; j < 8; j++) {
        int gi = (row0 + j) * 512 + tid;
        rs[j][tid] = zp[gi] + r[gi];
    }
    __syncthreads();
    {
        float s = 0.f;
        for (int c = lane; c < 512; c += 64) s += rs[wave][c];
#pragma unroll
        for (int o = 32; o; o >>= 1) s += __shfl_xor(s, o, 64);
        float mu = s * (1.f / 512.f);
        float v = 0.f;
        for (int c = lane; c < 512; c += 64) { float dx = rs[wave][c] - mu; v += dx * dx; }
#pragma unroll
        for (int o = 32; o; o >>= 1) v += __shfl_xor(v, o, 64);
        if (lane == 0) { sm[wave] = mu; si[wave] = rsqrtf(v * (1.f / 512.f) + 1e-6f); }
    }
    __syncthreads();
#pragma unroll
    for (int j = 0; j < 8; j++) {
        float val = (rs[j][tid] - sm[j]) * si[j] * g[tid] + be[tid];
        rs[j][tid] = val;
        if (blockIdx.x == 0) o1[(row0 + j) * 512 + tid] = val;
    }
    __syncthreads();
    float acc[8] = {0,0,0,0,0,0,0,0};
    const float* Wp = W1 + (kq * 64) * NDFF + colg;
#pragma unroll 8
    for (int d = 0; d < 64; d++) {
        float wv = Wp[d * NDFF];
#pragma unroll
        for (int p = 0; p < 8; p++) acc[p] += rs[p][kq * 64 + d] * wv;
    }
    __syncthreads();
    float (*part)[8][64] = (float(*)[8][64])rs;
#pragma unroll
    for (int p = 0; p < 8; p++) part[kq][p][col] = acc[p];
    __syncthreads();
    {
        int p = tid >> 6, c = tid & 63;
        int cg = blockIdx.x * 64 + c;
        float v = 0.f;
#pragma unroll
        for (int k = 0; k < 8; k++) v += part[k][p][c];
        h1[(row0 + p) * NDFF + cg] = fmaxf(v + b1[cg], 0.f);
    }
}

// ===== ffn2 partials. grid (8, 16, 4), 512 thr =====
__global__ __launch_bounds__(512)
void k_ffn2p(const float* __restrict__ h1, const float* __restrict__ W2,
             float* __restrict__ f2p)
{
    int tid = threadIdx.x;
    int col = tid & 63, kq = tid >> 6;
    int colg = blockIdx.x * 64 + col;
    int row0 = blockIdx.y * 8;
    int ks = blockIdx.z;
    __shared__ float rs[8][512];
#pragma unroll
    for (int j = 0; j < 8; j++)
        rs[j][tid] = h1[(row0 + j) * NDFF + ks * 512 + tid];
    __syncthreads();
    float acc[8] = {0,0,0,0,0,0,0,0};
    const float* Wp = W2 + (ks * 512 + kq * 64) * 512 + colg;
#pragma unroll 8
    for (int d = 0; d < 64; d++) {
        float wv = Wp[d * 512];
#pragma unroll
        for (int p = 0; p < 8; p++) acc[p] += rs[p][kq * 64 + d] * wv;
    }
    __syncthreads();
    float (*part)[8][64] = (float(*)[8][64])rs;
#pragma unroll
    for (int p = 0; p < 8; p++) part[kq][p][col] = acc[p];
    __syncthreads();
    {
        int p = tid >> 6, c = tid & 63;
        int cg = blockIdx.x * 64 + c;
        float v = 0.f;
#pragma unroll
        for (int k = 0; k < 8; k++) v += part[k][p][c];
        f2p[ks * 65536 + (row0 + p) * 512 + cg] = v;
    }
}

// ===== pred + fused LN3. grid (40, 8), 512 thr; 2-way K-split =====
__global__ __launch_bounds__(512)
void k_pred(const float* __restrict__ f2p, const float* __restrict__ b2,
            const float* __restrict__ o1, const float* __restrict__ g3,
            const float* __restrict__ b3, const float* __restrict__ Wout,
            const float* __restrict__ bout, float* __restrict__ pred)
{
    int tid = threadIdx.x;
    int col = tid & 255, kh = tid >> 8;
    int colg = blockIdx.x * 256 + col;
    int colL = min(colg, NVOC - 1);
    int row0 = blockIdx.y * 16;
    __shared__ float rs[16][512];
    __shared__ float sm[16], si[16];
    int wave = tid >> 6, lane = tid & 63;
#pragma unroll
    for (int j = 0; j < 16; j++) {
        int gi = (row0 + j) * 512 + tid;
        rs[j][tid] = f2p[gi] + f2p[65536 + gi] + f2p[131072 + gi] + f2p[196608 + gi]
                   + b2[tid] + o1[gi];
    }
    __syncthreads();
    {
        int row = wave * 2 + (lane >> 5);
        int l = lane & 31;
        float s = 0.f;
        for (int c = l; c < 512; c += 32) s += rs[row][c];
#pragma unroll
        for (int o = 16; o; o >>= 1) s += __shfl_xor(s, o, 64);
        float mu = s * (1.f / 512.f);
        float v = 0.f;
        for (int c = l; c < 512; c += 32) { float dx = rs[row][c] - mu; v += dx * dx; }
#pragma unroll
        for (int o = 16; o; o >>= 1) v += __shfl_xor(v, o, 64);
        if (l == 0) { sm[row] = mu; si[row] = rsqrtf(v * (1.f / 512.f) + 1e-6f); }
    }
    __syncthreads();
#pragma unroll
    for (int j = 0; j < 16; j++)
        rs[j][tid] = (rs[j][tid] - sm[j]) * si[j] * g3[tid] + b3[tid];
    __syncthreads();
    float acc[16];
#pragma unroll
    for (int p = 0; p < 16; p++) acc[p] = 0.f;
    const float* Wp = Wout + (kh * 256) * NVOC + colL;
#pragma unroll 4
    for (int d = 0; d < 256; d++) {
        float wv = Wp[d * NVOC];
#pragma unroll
        for (int p = 0; p < 16; p++) acc[p] += rs[p][kh * 256 + d] * wv;
    }
    __syncthreads();
    float (*part)[256] = (float(*)[256])rs;
    if (kh == 1) {
#pragma unroll
        for (int p = 0; p < 16; p++) part[p][col] = acc[p];
    }
    __syncthreads();
    if (kh == 0 && colg < NVOC) {
        float bv = bout[colg];
#pragma unroll
        for (int p = 0; p < 16; p++)
            pred[(row0 + p) * NVOC + colg] = acc[p] + part[p][col] + bv;
    }
}

// ===== per-row softmax stats + w_sq + attn_weights. grid 128, 512 thr =====
__global__ __launch_bounds__(512)
void k_soft(const float* __restrict__ pred, const int* __restrict__ x,
            const float* __restrict__ scw, const int* __restrict__ t_ptr,
            float* __restrict__ rowmax, float* __restrict__ rowsum,
            float* __restrict__ wsq, float* __restrict__ out)
{
    __shared__ float red[8];
    int row = blockIdx.x, tid = threadIdx.x;
    {
        int t = *t_ptr;
        float a = 0.f;
        if (tid <= t) {
#pragma unroll
            for (int hh = 0; hh < 8; hh++) a += scw[(row * 8 + hh) * 512 + tid];
            a *= 0.125f;
        }
        out[O6 + row * 512 + tid] = a;
    }
    const float* pr = pred + row * NVOC;
    float m = -3.0e38f;
    for (int v = tid; v < NVOC; v += 512) m = fmaxf(m, pr[v]);
#pragma unroll
    for (int o = 32; o; o >>= 1) m = fmaxf(m, __shfl_xor(m, o, 64));
    if ((tid & 63) == 0) red[tid >> 6] = m;
    __syncthreads();
#pragma unroll
    for (int i = 0; i < 8; i++) m = fmaxf(m, red[i]);
    __syncthreads();
    float s = 0.f;
    for (int v = tid; v < NVOC; v += 512) s += __expf(pr[v] - m);
#pragma unroll
    for (int o = 32; o; o >>= 1) s += __shfl_xor(s, o, 64);
    if ((tid & 63) == 0) red[tid >> 6] = s;
    __syncthreads();
    if (tid == 0) {
        float tot = 0.f;
#pragma unroll
        for (int i = 0; i < 8; i++) tot += red[i];
        rowmax[row] = m; rowsum[row] = tot;
        int b = row >> 4;
        float w = __expf(pr[x[b]] - m) / tot;
        wsq[row] = w;
        out[O9 + row] = w;
    }
}

// ===== vocab outputs + it/amw. grid (20, 8), 512 thr =====
__global__ __launch_bounds__(512)
void k_vocab(const float* __restrict__ pred, const float* __restrict__ rowmax,
             const float* __restrict__ rowsum, const float* __restrict__ wsq,
             const float* __restrict__ gumbel, int* __restrict__ it,
             float* __restrict__ out)
{
    int b = blockIdx.y;
    int tid = threadIdx.x;
    __shared__ int s_amw;
    if (tid == 0) {
        float bw = -3.0e38f; int bj = 0;
#pragma unroll
        for (int pp = 0; pp < 16; pp++) {
            float wv = wsq[b * 16 + pp];
            if (wv > bw) { bw = wv; bj = pp; }
        }
        s_amw = bj;
    }
    if (blockIdx.x == 0 && tid < 16) {
        float best = -3.0e38f; int bi = 0;
#pragma unroll
        for (int pp = 0; pp < 16; pp++) {
            float v = logf(wsq[b * 16 + pp] + 1e-10f) + gumbel[(b * 16 + tid) * 16 + pp];
            if (v > best) { best = v; bi = pp; }
        }
        it[b * 16 + tid] = bi;
    }
    __syncthreads();
    int v = blockIdx.x * 512 + tid;
    if (v >= NVOC) return;
    int amw = s_amw;
    float ga = 0.f, as = 0.f;
#pragma unroll
    for (int p = 0; p < 16; p++) {
        int rr = b * 16 + p;
        float pv = pred[rr * NVOC + v];
        ga += pv;
        as += __expf(pv - rowmax[rr]) * (1.f / rowsum[rr]);
    }
    out[O3 + b * NVOC + v] = ga * (1.f / 16.f);
    out[O2 + b * NVOC + v] = as * (1.f / 16.f);
    out[O4 + b * NVOC + v] = pred[(b * 16 + amw) * NVOC + v];
}

// ===== K / Vs resample + misc outputs. grid 4096 x 256 grid-stride =====
__global__ __launch_bounds__(256)
void k_resample(const float* __restrict__ Kin, const float* __restrict__ kws,
                const int* __restrict__ it, const int* __restrict__ t_ptr,
                const float* __restrict__ r, const float* __restrict__ epsz,
                const float* __restrict__ zws, const int* __restrict__ Iin,
                float* __restrict__ out)
{
    int t = *t_ptr;
    const f32x4* K4  = (const f32x4*)Kin;
    const f32x4* kw4 = (const f32x4*)kws;
    const f32x4* r4  = (const f32x4*)r;
    const f32x4* e4  = (const f32x4*)epsz;
    const f32x4* z4  = (const f32x4*)zws;
    f32x4* oK = (f32x4*)(out + O7);
    f32x4* oV = (f32x4*)(out + O8);
    const int total = 128 * 512 * 128;
    const int total2 = total + 16384;
    for (int i = blockIdx.x * 256 + threadIdx.x; i < total2; i += gridDim.x * 256) {
        if (i < total) {
            int lane = i & 127;
            int row = i >> 7;
            int s = row & 511;
            int bp = row >> 9;
            int b = bp >> 4;
            f32x4 vK, vV;
            if (s > t) {
                vK = __builtin_nontemporal_load(&K4[i]);
                vV = vK;
            } else {
                int ip = it[bp];
                int ip2 = it[b * 16 + ip];
                if (s == t) {
                    vK = kw4[(b * 16 + ip) * 128 + lane];
                    vV = kw4[(b * 16 + ip2) * 128 + lane];
                } else {
                    vK = K4[((b * 16 + ip) * 512 + s) * 128 + lane];
                    vV = K4[((b * 16 + ip2) * 512 + s) * 128 + lane];
                }
            }
            __builtin_nontemporal_store(vK, &oK[i]);
            __builtin_nontemporal_store(vV, &oV[i]);
        } else {
            int j = i - total;
            int fidx = j * 4;
            ((f32x4*)(out + O0))[j] = r4[j];
            ((f32x4*)(out + O5))[j] = e4[j];
            int row = fidx >> 9, d0 = fidx & 511;
            int b = row >> 4;
            int ip = it[row];
            ((f32x4*)(out + O1))[j] = z4[((b * 16 + ip) << 7) + (d0 >> 2)];
#pragma unroll
            for (int k = 0; k < 4; k++) {
                int s = d0 + k;
                float iv;
                if (s < t)       iv = (float)Iin[((b * 16 + ip) << 9) + s];
                else if (s == t) iv = (float)ip;
                else             iv = (float)Iin[row * 512 + s];
                out[O10 + fidx + k] = iv;
            }
        }
    }
}

extern "C" void kernel_launch(void* const* d_in, const int* in_sizes, int n_in,
                              void* d_out, int out_size, void* d_ws, size_t ws_size,
                              hipStream_t stream) {
    const float* r      = (const float*)d_in[0];
    const int*   x      = (const int*)d_in[1];
    const float* Kin    = (const float*)d_in[2];
    const float* Vin    = (const float*)d_in[3];
    const int*   Iin    = (const int*)d_in[5];
    const int*   t_ptr  = (const int*)d_in[6];
    const float* eps_q  = (const float*)d_in[7];
    const float* eps_k  = (const float*)d_in[8];
    const float* eps_v  = (const float*)d_in[9];
    const float* eps_z  = (const float*)d_in[10];
    const float* gumbel = (const float*)d_in[11];
    const float* Wq = (const float*)d_in[12]; const float* bq = (const float*)d_in[13];
    const float* Wk = (const float*)d_in[14]; const float* bk = (const float*)d_in[15];
    const float* Wv = (const float*)d_in[16]; const float* bv = (const float*)d_in[17];
    const float* Wo = (const float*)d_in[18]; const float* bo = (const float*)d_in[19];
    const float* ln1_g = (const float*)d_in[20]; const float* ln1_b = (const float*)d_in[21];
    const float* ln3_g = (const float*)d_in[22]; const float* ln3_b = (const float*)d_in[23];
    const float* W1 = (const float*)d_in[24]; const float* b1 = (const float*)d_in[25];
    const float* W2 = (const float*)d_in[26]; const float* b2 = (const float*)d_in[27];
    const float* Wout = (const float*)d_in[28]; const float* bout = (const float*)d_in[29];

    float* ws  = (float*)d_ws;
    float* q   = ws + WQ;
    float* kv  = ws + WK;
    float* vv  = ws + WV;
    float* zh  = ws + WZH;
    float* zp  = ws + WZ;
    float* o1  = ws + WO1;
    float* h1  = ws + WH1;
    float* pr  = ws + WPRED;
    float* rmx = ws + WMAX;
    float* rsm = ws + WSUM;
    float* wsq = ws + WWSQ;
    int*   itw = (int*)(ws + WIT);
    float* f2p = ws + WF2P;
    float* scw = ws + WSC;
    float* outp = (float*)d_out;

    k_qkv<<<dim3(8, 16, 3), 512, 0, stream>>>(r, Wq, bq, eps_q, q, Wk, bk, eps_k, kv, Wv, bv, eps_v, vv);
    k_attn<<<dim3(128, 8), 512, 0, stream>>>(q, kv, vv, Kin, Vin, t_ptr, zh, scw);
    k_zproj<<<dim3(8, 16), 512, 0, stream>>>(zh, Wo, bo, eps_z, zp);
    k_ffn1<<<dim3(32, 16), 512, 0, stream>>>(zp, r, ln1_g, ln1_b, W1, b1, o1, h1);
    k_ffn2p<<<dim3(8, 16, 4), 512, 0, stream>>>(h1, W2, f2p);
    k_pred<<<dim3(40, 8), 512, 0, stream>>>(f2p, b2, o1, ln3_g, ln3_b, Wout, bout, pr);
    k_soft<<<128, 512, 0, stream>>>(pr, x, scw, t_ptr, rmx, rsm, wsq, outp);
    k_vocab<<<dim3(20, 8), 512, 0, stream>>>(pr, rmx, rsm, wsq, gumbel, itw, outp);
    k_resample<<<4096, 256, 0, stream>>>(Kin, kv, itw, t_ptr, r, eps_z, zp, Iin, outp);
}